// Round 8
// baseline (604.917 us; speedup 1.0000x reference)
//
#include <hip/hip_runtime.h>

#define NN 8192
#define TT 1024
#define WW 64
#define HH 256
#define NPB 8
#define DTF (1.0f/24.0f)

__device__ __forceinline__ float sigmoidf_(float v) { return 1.0f / (1.0f + __expf(-v)); }

// ---------------- MLP -> (k, xw) -> IRF[n][64] in ws ----------------
__global__ __launch_bounds__(256) void mlp_kernel(
    const float* __restrict__ phys,
    const float* __restrict__ w1, const float* __restrict__ b1,
    const float* __restrict__ w2, const float* __restrict__ b2,
    const float* __restrict__ w3, const float* __restrict__ b3,
    float* __restrict__ irf)
{
    const int n0 = blockIdx.x * NPB;
    const int j  = threadIdx.x;

    __shared__ float s_phys[NPB * 3];
    __shared__ __align__(16) float s_h1[NPB * HH];   // 8 KB
    __shared__ float s_red[4][NPB][2];
    __shared__ float s_kxw[NPB][2];

    if (j < NPB * 3) s_phys[j] = phys[n0 * 3 + j];
    __syncthreads();

    const float w1v0 = w1[j], w1v1 = w1[HH + j], w1v2 = w1[2 * HH + j], b1v = b1[j];
#pragma unroll
    for (int m = 0; m < NPB; ++m) {
        float h = s_phys[m*3+0] * w1v0 + s_phys[m*3+1] * w1v1 + s_phys[m*3+2] * w1v2 + b1v;
        s_h1[m * HH + j] = fmaxf(h, 0.0f);
    }
    __syncthreads();

    float acc[NPB];
#pragma unroll
    for (int m = 0; m < NPB; ++m) acc[m] = 0.0f;
#pragma unroll 4
    for (int i4 = 0; i4 < HH / 4; ++i4) {
        const int i = i4 * 4;
        const float wv0 = w2[(i + 0) * HH + j];
        const float wv1 = w2[(i + 1) * HH + j];
        const float wv2 = w2[(i + 2) * HH + j];
        const float wv3 = w2[(i + 3) * HH + j];
#pragma unroll
        for (int m = 0; m < NPB; ++m) {
            const float4 h4 = *(const float4*)&s_h1[m * HH + i];
            acc[m] += h4.x * wv0 + h4.y * wv1 + h4.z * wv2 + h4.w * wv3;
        }
    }

    const float b2v = b2[j];
    const float w30 = w3[j * 2 + 0], w31 = w3[j * 2 + 1];
    const int wv = j >> 6;

#pragma unroll
    for (int m = 0; m < NPB; ++m) {
        const float h2 = fmaxf(acc[m] + b2v, 0.0f);
        float r0 = h2 * w30;
        float r1 = h2 * w31;
#pragma unroll
        for (int o = 32; o >= 1; o >>= 1) {
            r0 += __shfl_xor(r0, o);
            r1 += __shfl_xor(r1, o);
        }
        if ((j & 63) == 0) { s_red[wv][m][0] = r0; s_red[wv][m][1] = r1; }
    }
    __syncthreads();

    if (j < NPB * 2) {
        const int m = j >> 1, d = j & 1;
        float raw = s_red[0][m][d] + s_red[1][m][d] + s_red[2][m][d] + s_red[3][m][d] + b3[d];
        float p;
        if (d == 0) p = sigmoidf_(raw) * 0.25f + 0.005f;          // k
        else        p = sigmoidf_(raw - 3.0f) * 1.2f;             // xw
        s_kxw[m][d] = p;
    }
    __syncthreads();

    {
        const int m = j >> 5, l = j & 31;
        const float k  = s_kxw[m][0];
        const float xw = s_kxw[m][1];
        const float delay = k * xw;
        const float tau   = fmaxf(k * (1.0f - xw), 0.5f * DTF);
        const float t0f = l * DTF, t1f = (l + 32) * DTF;
        float h0 = (t0f >= delay) ? __expf(-(t0f - delay) / tau) / tau : 0.0f;
        float h1 = (t1f >= delay) ? __expf(-(t1f - delay) / tau) / tau : 0.0f;
        float s = h0 + h1;
#pragma unroll
        for (int o = 16; o >= 1; o >>= 1) s += __shfl_xor(s, o);
        const float inv = 1.0f / (s + 1e-8f);
        float* dst = irf + (size_t)(n0 + m) * WW;
        dst[l]      = h0 * inv;
        dst[l + 32] = h1 * inv;
    }
}

// ---------------- one routing task: register conv + lane shuffles (no LDS) ----------------
// out[n] = irf_n (x) (x[n] + sum_children out[c]); children 4n+1..4n+4
// (node 2047's 4th child 8192 is OOB -> per-child check). LEAF skips child loads.
template<int OT, bool LEAF>
__device__ __forceinline__ void conv_task(
    const float* __restrict__ x, const float* __restrict__ irf,
    float* __restrict__ out, int base_node, int r, int tid)
{
    constexpr int SEG  = 64 * OT;
    constexpr int NSEG = TT / SEG;
    constexpr int NH   = WW / OT;

    const int seg = (NSEG > 1) ? (r % NSEG) : 0;
    const int rb  = (NSEG > 1) ? (r / NSEG) : r;
    const int b   = rb & 1;
    const int n   = __builtin_amdgcn_readfirstlane(base_node + (rb >> 1));
    const size_t rowb = ((size_t)b * NN + n) * TT;
    const int t0  = seg * SEG;
    const int c0  = 4 * n + 1;
    const int loc = t0 + tid * OT;

    float a[OT];
#pragma unroll
    for (int u = 0; u < OT / 4; ++u) {
        float4 v = *(const float4*)&x[rowb + loc + 4 * u];
        if (!LEAF) {
#pragma unroll
            for (int e = 0; e < 4; ++e) {
                const int c = c0 + e;
                if (c < NN) {
                    const float4 w = *(const float4*)&out[((size_t)b * NN + c) * TT + loc + 4 * u];
                    v.x += w.x; v.y += w.y; v.z += w.z; v.w += w.w;
                }
            }
        }
        a[4*u+0] = v.x; a[4*u+1] = v.y; a[4*u+2] = v.z; a[4*u+3] = v.w;
    }

    float hbv = 0.0f;
    if (NSEG > 1 && seg > 0) {
        const int g = t0 - WW + tid;
        hbv = x[rowb + g];
        if (!LEAF) {
#pragma unroll
            for (int e = 0; e < 4; ++e) {
                const int c = c0 + e;
                if (c < NN) hbv += out[((size_t)b * NN + c) * TT + g];
            }
        }
    }

    float rf[WW];
    const float* irp = irf + (size_t)n * WW;
#pragma unroll
    for (int i = 0; i < WW / 4; ++i) {
        const float4 f = *(const float4*)&irp[4 * i];
        rf[4*i+0] = f.x; rf[4*i+1] = f.y; rf[4*i+2] = f.z; rf[4*i+3] = f.w;
    }

    float y[OT];
#pragma unroll
    for (int j = 0; j < OT; ++j) y[j] = 0.0f;

#pragma unroll
    for (int m = 0; m < OT; ++m)
#pragma unroll
        for (int j = m; j < OT; ++j)
            y[j] += rf[j - m] * a[m];

#pragma unroll
    for (int d = 1; d <= NH; ++d) {
        float h[OT];
#pragma unroll
        for (int m = 0; m < OT; ++m) {
            const float ha = __shfl(a[m], tid - d);
            float hv;
            if (NSEG > 1) {
                const float hh = __shfl(hbv, (WW + OT * (tid - d) + m) & 63);
                hv = (tid >= d) ? ha : ((seg > 0) ? hh : 0.0f);
            } else {
                hv = (tid >= d) ? ha : 0.0f;
            }
            h[m] = hv;
        }
        if (d < NH) {
#pragma unroll
            for (int m = 0; m < OT; ++m)
#pragma unroll
                for (int j = 0; j < OT; ++j)
                    y[j] += rf[j + OT * d - m] * h[m];
        } else {
#pragma unroll
            for (int m = 1; m < OT; ++m)
#pragma unroll
                for (int j = 0; j < m; ++j)
                    y[j] += rf[j + WW - m] * h[m];
        }
    }

#pragma unroll
    for (int j4 = 0; j4 < OT / 4; ++j4)
        *(float4*)&out[rowb + loc + 4 * j4] =
            make_float4(y[4*j4+0], y[4*j4+1], y[4*j4+2], y[4*j4+3]);
}

// ---------------- fused routing: leaf phase + 7 internal levels, 1 dispatch ----------------
// Grid 512 blocks x 256 thr = 8 waves/CU; co-resident for any VGPR<=256 -> spin barrier safe.
// single_phase >= 0: run only that phase, no barriers (fallback path, ws too small).
__global__ __launch_bounds__(256) void route_fused(
    const float* __restrict__ x,
    const float* __restrict__ irf,
    float* __restrict__ out,
    unsigned* __restrict__ ctr,
    int nblocks, int single_phase)
{
    const int wid = threadIdx.x >> 6;
    const int tid = threadIdx.x & 63;
    const int gw  = blockIdx.x * 4 + wid;
    const int GW  = nblocks * 4;
    const int sp  = single_phase;

    auto barrier = [&](int phase) {
        if (sp >= 0) return;
        __syncthreads();
        if (threadIdx.x == 0) {
            __threadfence();                      // release our out-writes (device scope)
            atomicAdd(ctr, 1u);
            const unsigned tgt = (unsigned)(phase * nblocks);
            while (__hip_atomic_load(ctr, __ATOMIC_ACQUIRE, __HIP_MEMORY_SCOPE_AGENT) < tgt)
                __builtin_amdgcn_s_sleep(2);
        }
        __syncthreads();
    };

    // phase 0: all leaves (n >= 2048), 6144 nodes x 2 batches
    if (sp < 0 || sp == 0)
        for (int t = gw; t < 12288; t += GW) conv_task<16, true>(x, irf, out, 2048, t, tid);
    barrier(1);
    // phase 1: L6 internal 1365..2047 (683)
    if (sp < 0 || sp == 1)
        for (int t = gw; t < 1366; t += GW) conv_task<16, false>(x, irf, out, 1365, t, tid);
    barrier(2);
    // phase 2: L5 341..1364 (1024)
    if (sp < 0 || sp == 2)
        for (int t = gw; t < 2048; t += GW) conv_task<16, false>(x, irf, out, 341, t, tid);
    barrier(3);
    // phase 3: L4 85..340 (256), OT=8 NSEG=2
    if (sp < 0 || sp == 3)
        for (int t = gw; t < 1024; t += GW) conv_task<8, false>(x, irf, out, 85, t, tid);
    barrier(4);
    // phase 4: L3 21..84 (64), OT=4 NSEG=4
    if (sp < 0 || sp == 4)
        for (int t = gw; t < 512; t += GW) conv_task<4, false>(x, irf, out, 21, t, tid);
    barrier(5);
    // phase 5: L2 5..20 (16)
    if (sp < 0 || sp == 5)
        for (int t = gw; t < 128; t += GW) conv_task<4, false>(x, irf, out, 5, t, tid);
    barrier(6);
    // phase 6: L1 1..4 (4)
    if (sp < 0 || sp == 6)
        for (int t = gw; t < 32; t += GW) conv_task<4, false>(x, irf, out, 1, t, tid);
    barrier(7);
    // phase 7: L0 root
    if (sp < 0 || sp == 7)
        for (int t = gw; t < 8; t += GW) conv_task<4, false>(x, irf, out, 0, t, tid);
}

extern "C" void kernel_launch(void* const* d_in, const int* in_sizes, int n_in,
                              void* d_out, int out_size, void* d_ws, size_t ws_size,
                              hipStream_t stream) {
    const float* x    = (const float*)d_in[0];
    const float* phys = (const float*)d_in[1];
    const float* w1   = (const float*)d_in[2];
    const float* b1   = (const float*)d_in[3];
    const float* w2   = (const float*)d_in[4];
    const float* b2   = (const float*)d_in[5];
    const float* w3   = (const float*)d_in[6];
    const float* b3   = (const float*)d_in[7];
    // d_in[8] = parent, d_in[9] = depth: fixed 4-ary heap tree (children 4n+1..4n+4)

    float* out = (float*)d_out;
    float* irf = (float*)d_ws;                               // N*64 floats = 2 MB
    const size_t IRF_BYTES = (size_t)NN * WW * sizeof(float);
    unsigned* ctr = (unsigned*)((char*)d_ws + IRF_BYTES);    // barrier counter

    mlp_kernel<<<NN / NPB, 256, 0, stream>>>(phys, w1, b1, w2, b2, w3, b3, irf);

    const int NBLK = 512;
    if (ws_size >= IRF_BYTES + 64) {
        hipMemsetAsync(ctr, 0, sizeof(unsigned), stream);    // graph-legal async memset
        route_fused<<<NBLK, 256, 0, stream>>>(x, irf, out, ctr, NBLK, -1);
    } else {
        // fallback: one dispatch per phase (no barriers used)
        for (int p = 0; p < 8; ++p)
            route_fused<<<NBLK, 256, 0, stream>>>(x, irf, out, nullptr, NBLK, p);
    }
}

// Round 9
// 119.892 us; speedup vs baseline: 5.0455x; 5.0455x over previous
//
#include <hip/hip_runtime.h>

#define NN 8192
#define TT 1024
#define WW 64
#define HH 256
#define NPB 8
#define DTF (1.0f/24.0f)

__device__ __forceinline__ float sigmoidf_(float v) { return 1.0f / (1.0f + __expf(-v)); }

// ---------------- MLP -> (k, xw) -> IRF[n][64] in ws ----------------
__global__ __launch_bounds__(256) void mlp_kernel(
    const float* __restrict__ phys,
    const float* __restrict__ w1, const float* __restrict__ b1,
    const float* __restrict__ w2, const float* __restrict__ b2,
    const float* __restrict__ w3, const float* __restrict__ b3,
    float* __restrict__ irf)
{
    const int n0 = blockIdx.x * NPB;
    const int j  = threadIdx.x;

    __shared__ float s_phys[NPB * 3];
    __shared__ __align__(16) float s_h1[NPB * HH];   // 8 KB
    __shared__ float s_red[4][NPB][2];
    __shared__ float s_kxw[NPB][2];

    if (j < NPB * 3) s_phys[j] = phys[n0 * 3 + j];
    __syncthreads();

    const float w1v0 = w1[j], w1v1 = w1[HH + j], w1v2 = w1[2 * HH + j], b1v = b1[j];
#pragma unroll
    for (int m = 0; m < NPB; ++m) {
        float h = s_phys[m*3+0] * w1v0 + s_phys[m*3+1] * w1v1 + s_phys[m*3+2] * w1v2 + b1v;
        s_h1[m * HH + j] = fmaxf(h, 0.0f);
    }
    __syncthreads();

    float acc[NPB];
#pragma unroll
    for (int m = 0; m < NPB; ++m) acc[m] = 0.0f;
#pragma unroll 4
    for (int i4 = 0; i4 < HH / 4; ++i4) {
        const int i = i4 * 4;
        const float wv0 = w2[(i + 0) * HH + j];
        const float wv1 = w2[(i + 1) * HH + j];
        const float wv2 = w2[(i + 2) * HH + j];
        const float wv3 = w2[(i + 3) * HH + j];
#pragma unroll
        for (int m = 0; m < NPB; ++m) {
            const float4 h4 = *(const float4*)&s_h1[m * HH + i];
            acc[m] += h4.x * wv0 + h4.y * wv1 + h4.z * wv2 + h4.w * wv3;
        }
    }

    const float b2v = b2[j];
    const float w30 = w3[j * 2 + 0], w31 = w3[j * 2 + 1];
    const int wv = j >> 6;

#pragma unroll
    for (int m = 0; m < NPB; ++m) {
        const float h2 = fmaxf(acc[m] + b2v, 0.0f);
        float r0 = h2 * w30;
        float r1 = h2 * w31;
#pragma unroll
        for (int o = 32; o >= 1; o >>= 1) {
            r0 += __shfl_xor(r0, o);
            r1 += __shfl_xor(r1, o);
        }
        if ((j & 63) == 0) { s_red[wv][m][0] = r0; s_red[wv][m][1] = r1; }
    }
    __syncthreads();

    if (j < NPB * 2) {
        const int m = j >> 1, d = j & 1;
        float raw = s_red[0][m][d] + s_red[1][m][d] + s_red[2][m][d] + s_red[3][m][d] + b3[d];
        float p;
        if (d == 0) p = sigmoidf_(raw) * 0.25f + 0.005f;          // k
        else        p = sigmoidf_(raw - 3.0f) * 1.2f;             // xw
        s_kxw[m][d] = p;
    }
    __syncthreads();

    {
        const int m = j >> 5, l = j & 31;
        const float k  = s_kxw[m][0];
        const float xw = s_kxw[m][1];
        const float delay = k * xw;
        const float tau   = fmaxf(k * (1.0f - xw), 0.5f * DTF);
        const float t0f = l * DTF, t1f = (l + 32) * DTF;
        float h0 = (t0f >= delay) ? __expf(-(t0f - delay) / tau) / tau : 0.0f;
        float h1 = (t1f >= delay) ? __expf(-(t1f - delay) / tau) / tau : 0.0f;
        float s = h0 + h1;
#pragma unroll
        for (int o = 16; o >= 1; o >>= 1) s += __shfl_xor(s, o);
        const float inv = 1.0f / (s + 1e-8f);
        float* dst = irf + (size_t)(n0 + m) * WW;
        dst[l]      = h0 * inv;
        dst[l + 32] = h1 * inv;
    }
}

// ---------------- shared conv helpers (full row, one wave, 16 outputs/thread) ----------------
__device__ __forceinline__ void load_rf(const float* __restrict__ irf, int n, float (&rf)[WW]) {
    const float* irp = irf + (size_t)n * WW;
#pragma unroll
    for (int i = 0; i < WW / 4; ++i) {
        const float4 f = *(const float4*)&irp[4 * i];
        rf[4*i+0] = f.x; rf[4*i+1] = f.y; rf[4*i+2] = f.z; rf[4*i+3] = f.w;
    }
}

// causal 64-tap conv of a wave-distributed row (lane owns a[16] consecutive),
// zeros before row start; halo via lane shuffles (no LDS).
__device__ __forceinline__ void wave_conv16(const float (&a)[16], const float (&rf)[WW],
                                            float (&y)[16], int tid)
{
#pragma unroll
    for (int j = 0; j < 16; ++j) y[j] = 0.0f;

#pragma unroll
    for (int m = 0; m < 16; ++m)
#pragma unroll
        for (int j = m; j < 16; ++j)
            y[j] += rf[j - m] * a[m];

#pragma unroll
    for (int d = 1; d <= 4; ++d) {
        float h[16];
#pragma unroll
        for (int m = 0; m < 16; ++m) {
            const float ha = __shfl(a[m], tid - d);
            h[m] = (tid >= d) ? ha : 0.0f;
        }
        if (d < 4) {
#pragma unroll
            for (int m = 0; m < 16; ++m)
#pragma unroll
                for (int j = 0; j < 16; ++j)
                    y[j] += rf[j + 16 * d - m] * h[m];
        } else {
#pragma unroll
            for (int m = 1; m < 16; ++m)
#pragma unroll
                for (int j = 0; j < m; ++j)
                    y[j] += rf[j + WW - m] * h[m];
        }
    }
}

// ---------------- leaf conv: nodes >= 2048 (no children), one wave per row ----------------
__global__ __launch_bounds__(256) void route_leaf(
    const float* __restrict__ x, const float* __restrict__ irf,
    float* __restrict__ out, int n_tasks)
{
    const int wid = threadIdx.x >> 6;
    const int tid = threadIdx.x & 63;
    const int r   = blockIdx.x * 4 + wid;
    if (r >= n_tasks) return;

    const int b = r & 1;
    const int n = __builtin_amdgcn_readfirstlane(2048 + (r >> 1));
    const size_t rowb = ((size_t)b * NN + n) * TT;
    const int loc = tid * 16;

    float a[16];
#pragma unroll
    for (int u = 0; u < 4; ++u) {
        const float4 v = *(const float4*)&x[rowb + loc + 4 * u];
        a[4*u+0] = v.x; a[4*u+1] = v.y; a[4*u+2] = v.z; a[4*u+3] = v.w;
    }

    float rf[WW], y[16];
    load_rf(irf, n, rf);
    wave_conv16(a, rf, y, tid);

#pragma unroll
    for (int u = 0; u < 4; ++u)
        *(float4*)&out[rowb + loc + 4 * u] = make_float4(y[4*u+0], y[4*u+1], y[4*u+2], y[4*u+3]);
}

// ---------------- L6 internal: 1365..2047, one wave per row ----------------
// children 4n+1..4n+4; node 2047's 4th child 8192 is OOB -> per-child check.
__global__ __launch_bounds__(256) void route_l6(
    const float* __restrict__ x, const float* __restrict__ irf,
    float* __restrict__ out, int n_tasks)
{
    const int wid = threadIdx.x >> 6;
    const int tid = threadIdx.x & 63;
    const int r   = blockIdx.x * 4 + wid;
    if (r >= n_tasks) return;

    const int b = r & 1;
    const int n = __builtin_amdgcn_readfirstlane(1365 + (r >> 1));
    const size_t rowb = ((size_t)b * NN + n) * TT;
    const int loc = tid * 16;
    const int c0  = 4 * n + 1;

    float a[16];
#pragma unroll
    for (int u = 0; u < 4; ++u) {
        float4 v = *(const float4*)&x[rowb + loc + 4 * u];
#pragma unroll
        for (int e = 0; e < 4; ++e) {
            const int c = c0 + e;
            if (c < NN) {
                const float4 w = *(const float4*)&out[((size_t)b * NN + c) * TT + loc + 4 * u];
                v.x += w.x; v.y += w.y; v.z += w.z; v.w += w.w;
            }
        }
        a[4*u+0] = v.x; a[4*u+1] = v.y; a[4*u+2] = v.z; a[4*u+3] = v.w;
    }

    float rf[WW], y[16];
    load_rf(irf, n, rf);
    wave_conv16(a, rf, y, tid);

#pragma unroll
    for (int u = 0; u < 4; ++u)
        *(float4*)&out[rowb + loc + 4 * u] = make_float4(y[4*u+0], y[4*u+1], y[4*u+2], y[4*u+3]);
}

// ---------------- 3-level subtree, block-local fusion (NO grid barriers) ----------------
// Block owns top node p (= top_base + blockIdx/2, batch = blockIdx&1).
// Wave w owns child cw=4p+1+w. Phase A: 4 grandchildren of cw (global staging,
// conv, global store, accumulate into LDS child-acc row — wave-exclusive, race-free).
// Phase B: conv child row from LDS. __syncthreads. Phase C: wave 0 convs p.
// All nodes here have 4 valid in-range children (top_base ∈ {21, 0}).
__global__ __launch_bounds__(256) void route_tail3(
    const float* __restrict__ x, const float* __restrict__ irf,
    float* __restrict__ out, int top_base)
{
    const int wid = threadIdx.x >> 6;
    const int tid = threadIdx.x & 63;
    const int b   = blockIdx.x & 1;
    const int p   = top_base + (int)(blockIdx.x >> 1);

    __shared__ __align__(16) float s_ch[4][TT];   // 16 KB: child acc rows, then child out rows

    const int cw = 4 * p + 1 + wid;
    const size_t crow = ((size_t)b * NN + cw) * TT;
    const int loc = tid * 16;

    // init child acc = x[cw]
#pragma unroll
    for (int u = 0; u < 4; ++u)
        *(float4*)&s_ch[wid][loc + 4 * u] = *(const float4*)&x[crow + loc + 4 * u];

    float rf[WW], a[16], y[16];

    // phase A: 4 grandchildren (children of cw)
#pragma unroll 1
    for (int k = 0; k < 4; ++k) {
        const int g = 4 * cw + 1 + k;
        const size_t grow = ((size_t)b * NN + g) * TT;
#pragma unroll
        for (int u = 0; u < 4; ++u) {
            float4 v = *(const float4*)&x[grow + loc + 4 * u];
#pragma unroll
            for (int e = 0; e < 4; ++e) {
                const float4 w = *(const float4*)&out[((size_t)b * NN + (4 * g + 1 + e)) * TT + loc + 4 * u];
                v.x += w.x; v.y += w.y; v.z += w.z; v.w += w.w;
            }
            a[4*u+0] = v.x; a[4*u+1] = v.y; a[4*u+2] = v.z; a[4*u+3] = v.w;
        }
        load_rf(irf, g, rf);
        wave_conv16(a, rf, y, tid);
#pragma unroll
        for (int u = 0; u < 4; ++u) {
            *(float4*)&out[grow + loc + 4 * u] = make_float4(y[4*u+0], y[4*u+1], y[4*u+2], y[4*u+3]);
#pragma unroll
            for (int e = 0; e < 4; ++e) s_ch[wid][loc + 4*u + e] += y[4*u + e];
        }
    }

    // phase B: child row (own LDS row, fully staged to regs before overwrite)
#pragma unroll
    for (int u = 0; u < 4; ++u) {
        const float4 v = *(const float4*)&s_ch[wid][loc + 4 * u];
        a[4*u+0] = v.x; a[4*u+1] = v.y; a[4*u+2] = v.z; a[4*u+3] = v.w;
    }
    load_rf(irf, cw, rf);
    wave_conv16(a, rf, y, tid);
#pragma unroll
    for (int u = 0; u < 4; ++u) {
        const float4 f = make_float4(y[4*u+0], y[4*u+1], y[4*u+2], y[4*u+3]);
        *(float4*)&out[crow + loc + 4 * u] = f;
        *(float4*)&s_ch[wid][loc + 4 * u]  = f;      // in place: row already in regs
    }

    __syncthreads();

    // phase C: wave 0 computes p from x[p] + 4 child out rows (LDS)
    if (wid == 0) {
        const size_t prow = ((size_t)b * NN + p) * TT;
#pragma unroll
        for (int u = 0; u < 4; ++u) {
            float4 v = *(const float4*)&x[prow + loc + 4 * u];
#pragma unroll
            for (int w2 = 0; w2 < 4; ++w2) {
                const float4 cc = *(const float4*)&s_ch[w2][loc + 4 * u];
                v.x += cc.x; v.y += cc.y; v.z += cc.z; v.w += cc.w;
            }
            a[4*u+0] = v.x; a[4*u+1] = v.y; a[4*u+2] = v.z; a[4*u+3] = v.w;
        }
        load_rf(irf, p, rf);
        wave_conv16(a, rf, y, tid);
#pragma unroll
        for (int u = 0; u < 4; ++u)
            *(float4*)&out[prow + loc + 4 * u] = make_float4(y[4*u+0], y[4*u+1], y[4*u+2], y[4*u+3]);
    }
}

extern "C" void kernel_launch(void* const* d_in, const int* in_sizes, int n_in,
                              void* d_out, int out_size, void* d_ws, size_t ws_size,
                              hipStream_t stream) {
    const float* x    = (const float*)d_in[0];
    const float* phys = (const float*)d_in[1];
    const float* w1   = (const float*)d_in[2];
    const float* b1   = (const float*)d_in[3];
    const float* w2   = (const float*)d_in[4];
    const float* b2   = (const float*)d_in[5];
    const float* w3   = (const float*)d_in[6];
    const float* b3   = (const float*)d_in[7];
    // d_in[8] = parent, d_in[9] = depth: fixed 4-ary heap tree (children 4n+1..4n+4)

    float* out = (float*)d_out;
    float* irf = (float*)d_ws;   // N*64 floats = 2 MB

    mlp_kernel<<<NN / NPB, 256, 0, stream>>>(phys, w1, b1, w2, b2, w3, b3, irf);

    // 1) leaves n>=2048: 6144 nodes x 2 batches, fully parallel
    route_leaf<<<(12288 + 3) / 4, 256, 0, stream>>>(x, irf, out, 12288);
    // 2) L6 internal 1365..2047 (683 x 2 = 1366 rows)
    route_l6<<<(1366 + 3) / 4, 256, 0, stream>>>(x, irf, out, 1366);
    // 3) L5+L4+L3 fused per L3 node: 64 nodes x 2 batches = 128 blocks
    route_tail3<<<128, 256, 0, stream>>>(x, irf, out, 21);
    // 4) L2+L1+L0 fused per root: 1 node x 2 batches = 2 blocks
    route_tail3<<<2, 256, 0, stream>>>(x, irf, out, 0);
}